// Round 4
// baseline (221.873 us; speedup 1.0000x reference)
//
#include <hip/hip_runtime.h>

#define HDIM 128
#define BDIM 512

typedef __attribute__((ext_vector_type(8))) __bf16 bf16x8;
typedef __attribute__((ext_vector_type(4))) float  f32x4;
typedef __attribute__((ext_vector_type(2))) float  f32x2;

// ---------------- Kernel 1: P = F @ W via bf16 MFMA, K-split x4 waves/tile.
// grid: 512 blocks x 256 thr. (unchanged from round 2/3)
//  * compile-time K -> full unroll -> pipelined global loads.
//  * bid swizzle groups the 8 ntile-blocks of one (net,mtile) on one XCD.
// Layouts (gfx950 16x16x32_bf16, HW-verified m89/m91/m120):
//   A[m][k]: m = lane&15, k = (lane>>4)*8 + j
//   B[k][n]: n = lane&15, k = (lane>>4)*8 + j
//   D[row][col]: col = lane&15, row = (lane>>4)*4 + reg
template<int K>
__device__ __forceinline__ f32x4 proj_acc(const float* __restrict__ F,
                                          const float* __restrict__ W,
                                          int m0, int n0, int wv, int l)
{
    constexpr int Ks = K >> 2;            // 512 or 192 (both %32==0)
    const int q = l >> 4, ln = l & 15;
    const float* Fp = &F[(size_t)(m0 + ln) * K + wv * Ks + q * 8];
    const float* Wp = &W[(size_t)(wv * Ks + q * 8) * HDIM + n0 + ln];
    f32x4 acc = {0.f, 0.f, 0.f, 0.f};
    #pragma unroll
    for (int k0 = 0; k0 < Ks; k0 += 32) {
        const float4 fa0 = *(const float4*)(Fp + k0);
        const float4 fa1 = *(const float4*)(Fp + k0 + 4);
        bf16x8 a, b;
        a[0] = (__bf16)fa0.x; a[1] = (__bf16)fa0.y; a[2] = (__bf16)fa0.z; a[3] = (__bf16)fa0.w;
        a[4] = (__bf16)fa1.x; a[5] = (__bf16)fa1.y; a[6] = (__bf16)fa1.z; a[7] = (__bf16)fa1.w;
        #pragma unroll
        for (int j = 0; j < 8; ++j)
            b[j] = (__bf16)Wp[(size_t)(k0 + j) * HDIM];
        acc = __builtin_amdgcn_mfma_f32_16x16x32_bf16(a, b, acc, 0, 0, 0);
    }
    return acc;
}

__global__ __launch_bounds__(256) void proj_mfma(
    const float* __restrict__ Ft, const float* __restrict__ Fs,
    const float* __restrict__ Wt, const float* __restrict__ Ws,
    __bf16* __restrict__ Pbt, __bf16* __restrict__ Pbs)
{
    const int tid = threadIdx.x;
    const int wv = tid >> 6, l = tid & 63;

    const int bid = blockIdx.x;
    const int c  = bid & 7;               // XCD
    const int tt = bid >> 3;              // 0..63
    const int ntile = tt & 7;
    const int g  = ((tt >> 3) << 3) + c;  // mtile-group 0..63
    const int net = g >> 5, mtile = g & 31;

    const int m0 = mtile * 16, n0 = ntile * 16;

    f32x4 acc;
    __bf16* P;
    if (net == 0) { acc = proj_acc<2048>(Ft, Wt, m0, n0, wv, l); P = Pbt; }
    else          { acc = proj_acc<768 >(Fs, Ws, m0, n0, wv, l); P = Pbs; }

    __shared__ float lds[4 * 256];
    #pragma unroll
    for (int r = 0; r < 4; ++r) lds[wv * 256 + r * 64 + l] = acc[r];
    __syncthreads();

    {
        const float s = lds[tid] + lds[256 + tid] + lds[512 + tid] + lds[768 + tid];
        const int r = tid >> 6, l2 = tid & 63;
        const int row = m0 + ((l2 >> 4) << 2) + r;
        const int col = n0 + (l2 & 15);
        P[(size_t)row * HDIM + col] = (__bf16)s;
    }
}

// ---------------- Kernel 2: U/V = Pb @ W1 (+ analytic bias term) via MFMA.
// grid: 1024 blocks x 64 thr.
// NEW vs prev round: outputs stored as bf16 (pair_kernel stages bf16 in LDS
// so one ds_read_b128 covers 8 h-values).
__global__ __launch_bounds__(64) void uv_mfma(
    const __bf16* __restrict__ Pbt, const __bf16* __restrict__ Pbs,
    const float* __restrict__ bt, const float* __restrict__ bs,
    const float* __restrict__ W1, const float* __restrict__ b1,
    __bf16* __restrict__ Ut, __bf16* __restrict__ Vt,
    __bf16* __restrict__ Us, __bf16* __restrict__ Vs,
    float* __restrict__ out)
{
    const int t = blockIdx.x;
    const int net = t >> 9, uvh = (t >> 8) & 1;
    const int mtile = (t >> 3) & 31, ntile = t & 7;
    const int l = threadIdx.x;

    if (t == 0 && l == 0) out[0] = 0.f;   // zero atomic target for pair_kernel

    const __bf16* P   = net ? Pbs : Pbt;
    const float* bias = net ? bs : bt;
    __bf16* O = net ? (uvh ? Vs : Us) : (uvh ? Vt : Ut);
    const float* W1o = W1 + (size_t)uvh * HDIM * HDIM;

    const int m0 = mtile * 16, n0 = ntile * 16;
    const int q = l >> 4, ln = l & 15;
    const int arow = m0 + ln, bn = n0 + ln;

    f32x4 acc = {0.f, 0.f, 0.f, 0.f};
    float cpart = 0.f;
    #pragma unroll
    for (int k0 = 0; k0 < HDIM; k0 += 32) {
        const int ka = k0 + q * 8;
        bf16x8 a = *(const bf16x8*)&P[(size_t)arow * HDIM + ka];
        bf16x8 b;
        #pragma unroll
        for (int j = 0; j < 8; ++j) {
            const float w = W1o[(size_t)(ka + j) * HDIM + bn];
            b[j] = (__bf16)w;
            cpart = fmaf(bias[ka + j], w, cpart);
        }
        acc = __builtin_amdgcn_mfma_f32_16x16x32_bf16(a, b, acc, 0, 0, 0);
    }
    cpart += __shfl_xor(cpart, 16, 64);
    cpart += __shfl_xor(cpart, 32, 64);
    const float cfull = cpart + (uvh == 0 ? b1[bn] : 0.f);

    #pragma unroll
    for (int r = 0; r < 4; ++r) {
        const int row = m0 + q * 4 + r;
        O[(size_t)row * HDIM + bn] = (__bf16)(acc[r] + cfull);
    }
}

// ---------------- Kernel 3: pairwise relations.
// NEW vs prev round (the lever): LDS staged in bf16 -> one ds_read_b128 =
// 8 h-values (reads halve); 256 thr with 2x2 register blocking (best
// reads/output); single-stage (whole H=128 fits: 4 x 8.5 KB), one barrier;
// w2 read uniform from global (s_load, off the LDS pipe).
// LDS instr count/block: 4 waves x 16 h8-iters x 8 reads = 512 (was 1792).
// Row stride 136 ushorts (272 B): worst-case 2-way bank alias = free (m136).
__device__ __forceinline__ f32x2 bfpair(unsigned d) {
    f32x2 r;
    r.x = __uint_as_float(d << 16);
    r.y = __uint_as_float(d & 0xffff0000u);
    return r;
}

__global__ __launch_bounds__(256) void pair_kernel(
    const __bf16* __restrict__ Ut, const __bf16* __restrict__ Vt,
    const __bf16* __restrict__ Us, const __bf16* __restrict__ Vs,
    const float* __restrict__ W2, const float* __restrict__ b2,
    float* __restrict__ out)
{
    __shared__ alignas(16) unsigned short tU[32 * 136];
    __shared__ alignas(16) unsigned short tV[32 * 136];
    __shared__ alignas(16) unsigned short tP[32 * 136];
    __shared__ alignas(16) unsigned short tQ[32 * 136];
    __shared__ float red[256];

    const int tx = threadIdx.x, ty = threadIdx.y;   // (16, 16)
    const int tid = ty * 16 + tx;
    const int i0 = blockIdx.y * 32, j0 = blockIdx.x * 32;

    // stage: 512 slots (32 rows x 16 bf16x8-groups) per array, 2 per thread.
    #pragma unroll
    for (int it = 0; it < 2; ++it) {
        const int s = tid + it * 256;
        const int r = s >> 4, c8 = s & 15;
        *(uint4*)&tU[r * 136 + c8 * 8] = *(const uint4*)&Ut[(size_t)(i0 + r) * HDIM + c8 * 8];
        *(uint4*)&tV[r * 136 + c8 * 8] = *(const uint4*)&Vt[(size_t)(j0 + r) * HDIM + c8 * 8];
        *(uint4*)&tP[r * 136 + c8 * 8] = *(const uint4*)&Us[(size_t)(i0 + r) * HDIM + c8 * 8];
        *(uint4*)&tQ[r * 136 + c8 * 8] = *(const uint4*)&Vs[(size_t)(j0 + r) * HDIM + c8 * 8];
    }
    __syncthreads();

    f32x2 aT[2][2] = {{{0.f,0.f},{0.f,0.f}},{{0.f,0.f},{0.f,0.f}}};
    f32x2 aS[2][2] = {{{0.f,0.f},{0.f,0.f}},{{0.f,0.f},{0.f,0.f}}};
    const f32x2 z2 = {0.f, 0.f};
    const float4* W24 = (const float4*)W2;

    #pragma unroll
    for (int h8 = 0; h8 < 16; ++h8) {
        const float4 wA = W24[h8 * 2 + 0];      // uniform -> s_load
        const float4 wB = W24[h8 * 2 + 1];
        const f32x2 w[4] = {{wA.x, wA.y}, {wA.z, wA.w}, {wB.x, wB.y}, {wB.z, wB.w}};

        const uint4 du0 = *(const uint4*)&tU[(ty     ) * 136 + h8 * 8];
        const uint4 du1 = *(const uint4*)&tU[(ty + 16) * 136 + h8 * 8];
        const uint4 dv0 = *(const uint4*)&tV[(tx     ) * 136 + h8 * 8];
        const uint4 dv1 = *(const uint4*)&tV[(tx + 16) * 136 + h8 * 8];
        const uint4 dp0 = *(const uint4*)&tP[(ty     ) * 136 + h8 * 8];
        const uint4 dp1 = *(const uint4*)&tP[(ty + 16) * 136 + h8 * 8];
        const uint4 dq0 = *(const uint4*)&tQ[(tx     ) * 136 + h8 * 8];
        const uint4 dq1 = *(const uint4*)&tQ[(tx + 16) * 136 + h8 * 8];

        f32x2 u[2][4], v[2][4], p[2][4], q[2][4];
        u[0][0] = bfpair(du0.x); u[0][1] = bfpair(du0.y); u[0][2] = bfpair(du0.z); u[0][3] = bfpair(du0.w);
        u[1][0] = bfpair(du1.x); u[1][1] = bfpair(du1.y); u[1][2] = bfpair(du1.z); u[1][3] = bfpair(du1.w);
        v[0][0] = bfpair(dv0.x); v[0][1] = bfpair(dv0.y); v[0][2] = bfpair(dv0.z); v[0][3] = bfpair(dv0.w);
        v[1][0] = bfpair(dv1.x); v[1][1] = bfpair(dv1.y); v[1][2] = bfpair(dv1.z); v[1][3] = bfpair(dv1.w);
        p[0][0] = bfpair(dp0.x); p[0][1] = bfpair(dp0.y); p[0][2] = bfpair(dp0.z); p[0][3] = bfpair(dp0.w);
        p[1][0] = bfpair(dp1.x); p[1][1] = bfpair(dp1.y); p[1][2] = bfpair(dp1.z); p[1][3] = bfpair(dp1.w);
        q[0][0] = bfpair(dq0.x); q[0][1] = bfpair(dq0.y); q[0][2] = bfpair(dq0.z); q[0][3] = bfpair(dq0.w);
        q[1][0] = bfpair(dq1.x); q[1][1] = bfpair(dq1.y); q[1][2] = bfpair(dq1.z); q[1][3] = bfpair(dq1.w);

        #pragma unroll
        for (int a = 0; a < 2; ++a)
            #pragma unroll
            for (int b = 0; b < 2; ++b)
                #pragma unroll
                for (int k = 0; k < 4; ++k) {
                    f32x2 m1 = __builtin_elementwise_max(u[a][k] + v[b][k], z2);
                    aT[a][b] = __builtin_elementwise_fma(m1, w[k], aT[a][b]);
                    f32x2 m2 = __builtin_elementwise_max(p[a][k] + q[b][k], z2);
                    aS[a][b] = __builtin_elementwise_fma(m2, w[k], aS[a][b]);
                }
    }

    const float b2v = b2[0];
    float local = 0.f;
    #pragma unroll
    for (int a = 0; a < 2; ++a)
        #pragma unroll
        for (int b = 0; b < 2; ++b) {
            const int i = i0 + ty + 16 * a;
            const int j = j0 + tx + 16 * b;
            if (i != j) {
                const float sT = aT[a][b].x + aT[a][b].y;
                const float sS = aS[a][b].x + aS[a][b].y;
                const float tr = 1.f / (1.f + __expf(-(sT + b2v)));
                const float sr = 1.f / (1.f + __expf(-(sS + b2v)));
                const float d = sr - tr;
                local = fmaf(d, d, local);
            }
        }

    red[tid] = local;
    __syncthreads();
    #pragma unroll
    for (int s = 128; s > 0; s >>= 1) {
        if (tid < s) red[tid] += red[tid + s];
        __syncthreads();
    }
    if (tid == 0)
        atomicAdd(out, red[0] * (1.0f / ((float)BDIM * (float)BDIM)));
}

extern "C" void kernel_launch(void* const* d_in, const int* in_sizes, int n_in,
                              void* d_out, int out_size, void* d_ws, size_t ws_size,
                              hipStream_t stream) {
    const float* teacher = (const float*)d_in[0];   // [512,2048]
    const float* student = (const float*)d_in[1];   // [512,768]
    const float* Wt = (const float*)d_in[2];        // [2048,128]
    const float* bt = (const float*)d_in[3];        // [128]
    const float* Ws = (const float*)d_in[4];        // [768,128]
    const float* bs = (const float*)d_in[5];        // [128]
    const float* W1 = (const float*)d_in[6];        // [256,128]
    const float* b1 = (const float*)d_in[7];        // [128]
    const float* W2 = (const float*)d_in[8];        // [128,1]
    const float* b2 = (const float*)d_in[9];        // [1]
    float* out = (float*)d_out;

    const size_t M = (size_t)BDIM * HDIM;           // 65536 elements
    __bf16* Pbt = (__bf16*)d_ws;                    // [512][128] bf16
    __bf16* Pbs = Pbt + M;
    __bf16* Ut = Pbs + M;                           // U/V now bf16 too
    __bf16* Vt = Ut + M;
    __bf16* Us = Vt + M;
    __bf16* Vs = Us + M;

    proj_mfma<<<512, 256, 0, stream>>>(teacher, student, Wt, Ws, Pbt, Pbs);

    uv_mfma<<<1024, 64, 0, stream>>>(Pbt, Pbs, bt, bs, W1, b1,
                                     Ut, Vt, Us, Vs, out);

    pair_kernel<<<dim3(16, 16), dim3(16, 16), 0, stream>>>(
        Ut, Vt, Us, Vs, W2, b2, out);
}

// Round 5
// 95.840 us; speedup vs baseline: 2.3150x; 2.3150x over previous
//
#include <hip/hip_runtime.h>

#define HDIM 128
#define BDIM 512

typedef __attribute__((ext_vector_type(8))) __bf16 bf16x8;
typedef __attribute__((ext_vector_type(4))) float  f32x4;
typedef __attribute__((ext_vector_type(2))) float  f32x2;

// ---------------- Kernel 1: P = F @ W via bf16 MFMA, K-split x4 waves/tile.
// grid: 512 blocks x 256 thr. (unchanged)
//  * compile-time K -> full unroll -> pipelined global loads.
//  * bid swizzle groups the 8 ntile-blocks of one (net,mtile) on one XCD.
// Layouts (gfx950 16x16x32_bf16, HW-verified m89/m91/m120):
//   A[m][k]: m = lane&15, k = (lane>>4)*8 + j
//   B[k][n]: n = lane&15, k = (lane>>4)*8 + j
//   D[row][col]: col = lane&15, row = (lane>>4)*4 + reg
template<int K>
__device__ __forceinline__ f32x4 proj_acc(const float* __restrict__ F,
                                          const float* __restrict__ W,
                                          int m0, int n0, int wv, int l)
{
    constexpr int Ks = K >> 2;            // 512 or 192 (both %32==0)
    const int q = l >> 4, ln = l & 15;
    const float* Fp = &F[(size_t)(m0 + ln) * K + wv * Ks + q * 8];
    const float* Wp = &W[(size_t)(wv * Ks + q * 8) * HDIM + n0 + ln];
    f32x4 acc = {0.f, 0.f, 0.f, 0.f};
    #pragma unroll
    for (int k0 = 0; k0 < Ks; k0 += 32) {
        const float4 fa0 = *(const float4*)(Fp + k0);
        const float4 fa1 = *(const float4*)(Fp + k0 + 4);
        bf16x8 a, b;
        a[0] = (__bf16)fa0.x; a[1] = (__bf16)fa0.y; a[2] = (__bf16)fa0.z; a[3] = (__bf16)fa0.w;
        a[4] = (__bf16)fa1.x; a[5] = (__bf16)fa1.y; a[6] = (__bf16)fa1.z; a[7] = (__bf16)fa1.w;
        #pragma unroll
        for (int j = 0; j < 8; ++j)
            b[j] = (__bf16)Wp[(size_t)(k0 + j) * HDIM];
        acc = __builtin_amdgcn_mfma_f32_16x16x32_bf16(a, b, acc, 0, 0, 0);
    }
    return acc;
}

__global__ __launch_bounds__(256) void proj_mfma(
    const float* __restrict__ Ft, const float* __restrict__ Fs,
    const float* __restrict__ Wt, const float* __restrict__ Ws,
    __bf16* __restrict__ Pbt, __bf16* __restrict__ Pbs)
{
    const int tid = threadIdx.x;
    const int wv = tid >> 6, l = tid & 63;

    const int bid = blockIdx.x;
    const int c  = bid & 7;               // XCD
    const int tt = bid >> 3;              // 0..63
    const int ntile = tt & 7;
    const int g  = ((tt >> 3) << 3) + c;  // mtile-group 0..63
    const int net = g >> 5, mtile = g & 31;

    const int m0 = mtile * 16, n0 = ntile * 16;

    f32x4 acc;
    __bf16* P;
    if (net == 0) { acc = proj_acc<2048>(Ft, Wt, m0, n0, wv, l); P = Pbt; }
    else          { acc = proj_acc<768 >(Fs, Ws, m0, n0, wv, l); P = Pbs; }

    __shared__ float lds[4 * 256];
    #pragma unroll
    for (int r = 0; r < 4; ++r) lds[wv * 256 + r * 64 + l] = acc[r];
    __syncthreads();

    {
        const float s = lds[tid] + lds[256 + tid] + lds[512 + tid] + lds[768 + tid];
        const int r = tid >> 6, l2 = tid & 63;
        const int row = m0 + ((l2 >> 4) << 2) + r;
        const int col = n0 + (l2 & 15);
        P[(size_t)row * HDIM + col] = (__bf16)s;
    }
}

// ---------------- Kernel 2: U/V = Pb @ W1 (+ analytic bias term) via MFMA.
// grid: 1024 blocks x 64 thr. Outputs bf16 (pair stages bf16 in LDS).
__global__ __launch_bounds__(64) void uv_mfma(
    const __bf16* __restrict__ Pbt, const __bf16* __restrict__ Pbs,
    const float* __restrict__ bt, const float* __restrict__ bs,
    const float* __restrict__ W1, const float* __restrict__ b1,
    __bf16* __restrict__ Ut, __bf16* __restrict__ Vt,
    __bf16* __restrict__ Us, __bf16* __restrict__ Vs,
    float* __restrict__ out)
{
    const int t = blockIdx.x;
    const int net = t >> 9, uvh = (t >> 8) & 1;
    const int mtile = (t >> 3) & 31, ntile = t & 7;
    const int l = threadIdx.x;

    if (t == 0 && l == 0) out[0] = 0.f;   // zero atomic target for pair_kernel

    const __bf16* P   = net ? Pbs : Pbt;
    const float* bias = net ? bs : bt;
    __bf16* O = net ? (uvh ? Vs : Us) : (uvh ? Vt : Ut);
    const float* W1o = W1 + (size_t)uvh * HDIM * HDIM;

    const int m0 = mtile * 16, n0 = ntile * 16;
    const int q = l >> 4, ln = l & 15;
    const int arow = m0 + ln, bn = n0 + ln;

    f32x4 acc = {0.f, 0.f, 0.f, 0.f};
    float cpart = 0.f;
    #pragma unroll
    for (int k0 = 0; k0 < HDIM; k0 += 32) {
        const int ka = k0 + q * 8;
        bf16x8 a = *(const bf16x8*)&P[(size_t)arow * HDIM + ka];
        bf16x8 b;
        #pragma unroll
        for (int j = 0; j < 8; ++j) {
            const float w = W1o[(size_t)(ka + j) * HDIM + bn];
            b[j] = (__bf16)w;
            cpart = fmaf(bias[ka + j], w, cpart);
        }
        acc = __builtin_amdgcn_mfma_f32_16x16x32_bf16(a, b, acc, 0, 0, 0);
    }
    cpart += __shfl_xor(cpart, 16, 64);
    cpart += __shfl_xor(cpart, 32, 64);
    const float cfull = cpart + (uvh == 0 ? b1[bn] : 0.f);

    #pragma unroll
    for (int r = 0; r < 4; ++r) {
        const int row = m0 + q * 4 + r;
        O[(size_t)row * HDIM + bn] = (__bf16)(acc[r] + cfull);
    }
}

// ---------------- Kernel 3: pairwise relations, bf16 LDS staging.
// FIX vs round 4 (which spilled: VGPR=256, 263 MB scratch traffic):
//  * h8 loop unrolled only 2x (was 16x) -> bounded live ranges.
//  * each uint4 component converted & consumed IMMEDIATELY (no u[2][4]
//    arrays) -> live set ~ 8 uint4 + 16 acc regs.
//  * __launch_bounds__(256,4) pins allocator at <=128 VGPR (LDS already
//    caps at 4 blocks/CU, so 4 waves/EU is the natural occupancy).
// LDS instrs/block stay 512 (4 waves x 16 iters x 8 ds_read_b128).
__device__ __forceinline__ f32x2 bfpair(unsigned d) {
    f32x2 r;
    r.x = __uint_as_float(d << 16);
    r.y = __uint_as_float(d & 0xffff0000u);
    return r;
}

#define PAIR_STEP(DU0,DU1,DV0,DV1,DP0,DP1,DQ0,DQ1,WK)                         \
    {                                                                          \
        const f32x2 u0_ = bfpair(DU0), u1_ = bfpair(DU1);                      \
        const f32x2 v0_ = bfpair(DV0), v1_ = bfpair(DV1);                      \
        const f32x2 p0_ = bfpair(DP0), p1_ = bfpair(DP1);                      \
        const f32x2 q0_ = bfpair(DQ0), q1_ = bfpair(DQ1);                      \
        aT00 = __builtin_elementwise_fma(__builtin_elementwise_max(u0_+v0_,z2), WK, aT00); \
        aT01 = __builtin_elementwise_fma(__builtin_elementwise_max(u0_+v1_,z2), WK, aT01); \
        aT10 = __builtin_elementwise_fma(__builtin_elementwise_max(u1_+v0_,z2), WK, aT10); \
        aT11 = __builtin_elementwise_fma(__builtin_elementwise_max(u1_+v1_,z2), WK, aT11); \
        aS00 = __builtin_elementwise_fma(__builtin_elementwise_max(p0_+q0_,z2), WK, aS00); \
        aS01 = __builtin_elementwise_fma(__builtin_elementwise_max(p0_+q1_,z2), WK, aS01); \
        aS10 = __builtin_elementwise_fma(__builtin_elementwise_max(p1_+q0_,z2), WK, aS10); \
        aS11 = __builtin_elementwise_fma(__builtin_elementwise_max(p1_+q1_,z2), WK, aS11); \
    }

__global__ __launch_bounds__(256, 4) void pair_kernel(
    const __bf16* __restrict__ Ut, const __bf16* __restrict__ Vt,
    const __bf16* __restrict__ Us, const __bf16* __restrict__ Vs,
    const float* __restrict__ W2, const float* __restrict__ b2,
    float* __restrict__ out)
{
    __shared__ alignas(16) unsigned short tU[32 * 136];
    __shared__ alignas(16) unsigned short tV[32 * 136];
    __shared__ alignas(16) unsigned short tP[32 * 136];
    __shared__ alignas(16) unsigned short tQ[32 * 136];
    __shared__ float red[256];

    const int tx = threadIdx.x, ty = threadIdx.y;   // (16, 16)
    const int tid = ty * 16 + tx;
    const int i0 = blockIdx.y * 32, j0 = blockIdx.x * 32;

    // stage: 512 slots (32 rows x 16 bf16x8-groups) per array, 2 per thread.
    #pragma unroll
    for (int it = 0; it < 2; ++it) {
        const int s = tid + it * 256;
        const int r = s >> 4, c8 = s & 15;
        *(uint4*)&tU[r * 136 + c8 * 8] = *(const uint4*)&Ut[(size_t)(i0 + r) * HDIM + c8 * 8];
        *(uint4*)&tV[r * 136 + c8 * 8] = *(const uint4*)&Vt[(size_t)(j0 + r) * HDIM + c8 * 8];
        *(uint4*)&tP[r * 136 + c8 * 8] = *(const uint4*)&Us[(size_t)(i0 + r) * HDIM + c8 * 8];
        *(uint4*)&tQ[r * 136 + c8 * 8] = *(const uint4*)&Vs[(size_t)(j0 + r) * HDIM + c8 * 8];
    }
    __syncthreads();

    f32x2 aT00 = {0.f,0.f}, aT01 = {0.f,0.f}, aT10 = {0.f,0.f}, aT11 = {0.f,0.f};
    f32x2 aS00 = {0.f,0.f}, aS01 = {0.f,0.f}, aS10 = {0.f,0.f}, aS11 = {0.f,0.f};
    const f32x2 z2 = {0.f, 0.f};
    const float4* W24 = (const float4*)W2;

    #pragma unroll 2
    for (int h8 = 0; h8 < 16; ++h8) {
        const float4 wA = W24[h8 * 2 + 0];      // uniform -> s_load
        const float4 wB = W24[h8 * 2 + 1];
        const f32x2 w0 = {wA.x, wA.y}, w1 = {wA.z, wA.w};
        const f32x2 w2 = {wB.x, wB.y}, w3 = {wB.z, wB.w};

        const uint4 du0 = *(const uint4*)&tU[(ty     ) * 136 + h8 * 8];
        const uint4 du1 = *(const uint4*)&tU[(ty + 16) * 136 + h8 * 8];
        const uint4 dv0 = *(const uint4*)&tV[(tx     ) * 136 + h8 * 8];
        const uint4 dv1 = *(const uint4*)&tV[(tx + 16) * 136 + h8 * 8];
        const uint4 dp0 = *(const uint4*)&tP[(ty     ) * 136 + h8 * 8];
        const uint4 dp1 = *(const uint4*)&tP[(ty + 16) * 136 + h8 * 8];
        const uint4 dq0 = *(const uint4*)&tQ[(tx     ) * 136 + h8 * 8];
        const uint4 dq1 = *(const uint4*)&tQ[(tx + 16) * 136 + h8 * 8];

        PAIR_STEP(du0.x, du1.x, dv0.x, dv1.x, dp0.x, dp1.x, dq0.x, dq1.x, w0)
        PAIR_STEP(du0.y, du1.y, dv0.y, dv1.y, dp0.y, dp1.y, dq0.y, dq1.y, w1)
        PAIR_STEP(du0.z, du1.z, dv0.z, dv1.z, dp0.z, dp1.z, dq0.z, dq1.z, w2)
        PAIR_STEP(du0.w, du1.w, dv0.w, dv1.w, dp0.w, dp1.w, dq0.w, dq1.w, w3)
    }

    const float b2v = b2[0];
    float local = 0.f;
    {
        const float sT[2][2] = {{aT00.x + aT00.y, aT01.x + aT01.y},
                                {aT10.x + aT10.y, aT11.x + aT11.y}};
        const float sS[2][2] = {{aS00.x + aS00.y, aS01.x + aS01.y},
                                {aS10.x + aS10.y, aS11.x + aS11.y}};
        #pragma unroll
        for (int a = 0; a < 2; ++a)
            #pragma unroll
            for (int b = 0; b < 2; ++b) {
                const int i = i0 + ty + 16 * a;
                const int j = j0 + tx + 16 * b;
                if (i != j) {
                    const float tr = 1.f / (1.f + __expf(-(sT[a][b] + b2v)));
                    const float sr = 1.f / (1.f + __expf(-(sS[a][b] + b2v)));
                    const float d = sr - tr;
                    local = fmaf(d, d, local);
                }
            }
    }

    red[tid] = local;
    __syncthreads();
    #pragma unroll
    for (int s = 128; s > 0; s >>= 1) {
        if (tid < s) red[tid] += red[tid + s];
        __syncthreads();
    }
    if (tid == 0)
        atomicAdd(out, red[0] * (1.0f / ((float)BDIM * (float)BDIM)));
}

extern "C" void kernel_launch(void* const* d_in, const int* in_sizes, int n_in,
                              void* d_out, int out_size, void* d_ws, size_t ws_size,
                              hipStream_t stream) {
    const float* teacher = (const float*)d_in[0];   // [512,2048]
    const float* student = (const float*)d_in[1];   // [512,768]
    const float* Wt = (const float*)d_in[2];        // [2048,128]
    const float* bt = (const float*)d_in[3];        // [128]
    const float* Ws = (const float*)d_in[4];        // [768,128]
    const float* bs = (const float*)d_in[5];        // [128]
    const float* W1 = (const float*)d_in[6];        // [256,128]
    const float* b1 = (const float*)d_in[7];        // [128]
    const float* W2 = (const float*)d_in[8];        // [128,1]
    const float* b2 = (const float*)d_in[9];        // [1]
    float* out = (float*)d_out;

    const size_t M = (size_t)BDIM * HDIM;           // 65536 elements
    __bf16* Pbt = (__bf16*)d_ws;                    // [512][128] bf16
    __bf16* Pbs = Pbt + M;
    __bf16* Ut = Pbs + M;                           // U/V bf16
    __bf16* Vt = Ut + M;
    __bf16* Us = Vt + M;
    __bf16* Vs = Us + M;

    proj_mfma<<<512, 256, 0, stream>>>(teacher, student, Wt, Ws, Pbt, Pbs);

    uv_mfma<<<1024, 64, 0, stream>>>(Pbt, Pbs, bt, bs, W1, b1,
                                     Ut, Vt, Us, Vs, out);

    pair_kernel<<<dim3(16, 16), dim3(16, 16), 0, stream>>>(
        Ut, Vt, Us, Vs, W2, b2, out);
}